// Round 8
// baseline (252.500 us; speedup 1.0000x reference)
//
#include <hip/hip_runtime.h>

// (1/sqrt(3)) * log2(e): folds softmax scale AND exp->exp2 into q (applied in
// phase 1, so phase 2 reads pre-scaled q). Softmax is shift-invariant; scores
// are O(+-4) -> no max-subtraction needed in fp32 (validated rounds 1-7).
#define QSCALE 0.83294038f

// LDS layout: per element e (0..63): 16 rows of 18 floats [K0..5,V0..5,Q0..5],
// row stride 18, element stride 290 (16*18 + 2 pad, even -> 8B alignment kept;
// 290 mod 32 = 2 spreads elements across bank pairs). 74240 B -> 2 blocks/CU.
#define EROW 18
#define ESTRIDE 290
#define LDS_FLOATS (64 * ESTRIDE)

__device__ __forceinline__ int seg_of(int s) {
    // SEG = [0, 1*5, 2*3, 3, 4*6]
    return (s == 0) ? 0 : (s < 6) ? 1 : (s < 9) ? 2 : (s == 9) ? 3 : 4;
}

// Phase 1: wave = ONE position x 64 elements -> seg wave-uniform -> all
// weights are s_loads (SGPR operands, free in v_fma). [r7: VGPR=24 proved it]
// Phase 2 (after ONE barrier): 16-lane group = one element, lane = query pos
// -> every k-step's K|V row is read by 16 lanes at the SAME address = LDS
// broadcast. LDS data-pipe traffic drops 16x (786->49 KB/block), and outputs
// emerge in coalesced order (no OUT staging, no extra barriers).
__global__ __launch_bounds__(1024) void attn_seg_kernel(
    const float* __restrict__ x,
    const float* __restrict__ Wq, const float* __restrict__ bq,
    const float* __restrict__ Wk, const float* __restrict__ bk,
    const float* __restrict__ Wv, const float* __restrict__ bv,
    const float* __restrict__ Wo, const float* __restrict__ bo,
    float* __restrict__ out, int nelems)
{
    __shared__ __align__(16) float lds[LDS_FLOATS];
    const int t = threadIdx.x;
    const int ebase = (int)blockIdx.x << 6;

    // ================= phase 1: projections (wave = position) =============
    {
        const int e = t & 63;                                   // lane: element
        const int s = __builtin_amdgcn_readfirstlane(t >> 6);   // wave: position
        const int seg = seg_of(s);                              // uniform -> SALU

        float x0=0.f,x1=0.f,x2=0.f,x3=0.f,x4=0.f,x5=0.f;
        if (ebase + e < nelems) {
            const float* xp = x + (size_t)(ebase + e) * 96 + s * 6;
            float2 a = *(const float2*)(xp);
            float2 b = *(const float2*)(xp + 2);
            float2 c = *(const float2*)(xp + 4);
            x0=a.x; x1=a.y; x2=b.x; x3=b.y; x4=c.x; x5=c.y;
        }

        const float* wk = Wk + seg * 36;  const float* bkp = bk + seg * 6;
        const float* wv = Wv + seg * 36;  const float* bvp = bv + seg * 6;
        const float* wq = Wq + seg * 36;  const float* bqp = bq + seg * 6;

        float kk[6], vv[6], qq[6];
        #pragma unroll
        for (int j = 0; j < 6; ++j) {
            kk[j] = bkp[j] + x0*wk[j*6+0] + x1*wk[j*6+1] + x2*wk[j*6+2]
                           + x3*wk[j*6+3] + x4*wk[j*6+4] + x5*wk[j*6+5];
            vv[j] = bvp[j] + x0*wv[j*6+0] + x1*wv[j*6+1] + x2*wv[j*6+2]
                           + x3*wv[j*6+3] + x4*wv[j*6+4] + x5*wv[j*6+5];
            qq[j] = (bqp[j] + x0*wq[j*6+0] + x1*wq[j*6+1] + x2*wq[j*6+2]
                            + x3*wq[j*6+3] + x4*wq[j*6+4] + x5*wq[j*6+5]) * QSCALE;
        }

        float* row = &lds[e * ESTRIDE + s * EROW];
        *(float2*)(row + 0)  = make_float2(kk[0], kk[1]);
        *(float2*)(row + 2)  = make_float2(kk[2], kk[3]);
        *(float2*)(row + 4)  = make_float2(kk[4], kk[5]);
        *(float2*)(row + 6)  = make_float2(vv[0], vv[1]);
        *(float2*)(row + 8)  = make_float2(vv[2], vv[3]);
        *(float2*)(row + 10) = make_float2(vv[4], vv[5]);
        *(float2*)(row + 12) = make_float2(qq[0], qq[1]);
        *(float2*)(row + 14) = make_float2(qq[2], qq[3]);
        *(float2*)(row + 16) = make_float2(qq[4], qq[5]);
    }

    __syncthreads();   // the ONLY barrier

    // ============ phase 2: attention (16-lane group = element) ============
    {
        const int l  = t & 63;
        const int e2 = ((t >> 6) << 2) + (l >> 4);   // wave*4 + group
        const int qp = l & 15;                       // query position
        const float* eb = &lds[e2 * ESTRIDE];

        // own query (pre-scaled): per-lane address, stride 18 -> spread banks
        const float* qrow = eb + qp * EROW + 12;
        float2 qa = *(const float2*)(qrow);
        float2 qb = *(const float2*)(qrow + 2);
        float2 qc = *(const float2*)(qrow + 4);

        // fused scores -> exp2 -> sum -> PV; K|V rows group-uniform = broadcast
        float s0 = 0.f, s1 = 0.f;
        float c0=0.f,c1=0.f,c2=0.f,c3=0.f,c4=0.f,c5=0.f;
        #pragma unroll
        for (int k = 0; k < 16; ++k) {
            const float* row = eb + k * EROW;
            float2 ka = *(const float2*)(row);
            float2 kb = *(const float2*)(row + 2);
            float2 kc = *(const float2*)(row + 4);
            float e0 = __builtin_amdgcn_exp2f(qa.x*ka.x + qa.y*ka.y + qb.x*kb.x);
            float e1 = __builtin_amdgcn_exp2f(qb.y*kb.y + qc.x*kc.x + qc.y*kc.y);
            float2 va = *(const float2*)(row + 6);
            float2 vb = *(const float2*)(row + 8);
            float2 vc = *(const float2*)(row + 10);
            s0 += e0; s1 += e1;
            c0 += e0*va.x; c1 += e0*va.y; c2 += e0*vb.x;
            c3 += e1*vb.y; c4 += e1*vc.x; c5 += e1*vc.y;
        }
        const float i0 = __builtin_amdgcn_rcpf(s0);
        const float i1 = __builtin_amdgcn_rcpf(s1);
        c0 *= i0; c1 *= i0; c2 *= i0;
        c3 *= i1; c4 *= i1; c5 *= i1;

        // output projection: Wo,bo wave-uniform -> s_load/SGPR operands
        float o_[6];
        #pragma unroll
        for (int i = 0; i < 6; ++i) {
            o_[i] = bo[i] + c0*Wo[i*6+0] + c1*Wo[i*6+1] + c2*Wo[i*6+2]
                          + c3*Wo[i*6+3] + c4*Wo[i*6+4] + c5*Wo[i*6+5];
        }

        // direct coalesced store: lane qp -> contiguous 24B, group -> 384B run
        if (ebase + e2 < nelems) {
            float* op = out + (size_t)(ebase + e2) * 96 + qp * 6;
            *(float2*)(op)     = make_float2(o_[0], o_[1]);
            *(float2*)(op + 2) = make_float2(o_[2], o_[3]);
            *(float2*)(op + 4) = make_float2(o_[4], o_[5]);
        }
    }
}

extern "C" void kernel_launch(void* const* d_in, const int* in_sizes, int n_in,
                              void* d_out, int out_size, void* d_ws, size_t ws_size,
                              hipStream_t stream) {
    const float* x  = (const float*)d_in[0];
    const float* Wq = (const float*)d_in[1];
    const float* bq = (const float*)d_in[2];
    const float* Wk = (const float*)d_in[3];
    const float* bk = (const float*)d_in[4];
    const float* Wv = (const float*)d_in[5];
    const float* bv = (const float*)d_in[6];
    const float* Wo = (const float*)d_in[7];
    const float* bo = (const float*)d_in[8];
    float* out = (float*)d_out;

    const int nelems = in_sizes[0] / 96;        // batch elements
    const int grid   = (nelems + 63) / 64;      // 64 elements / block (1024 thr)
    attn_seg_kernel<<<grid, 1024, 0, stream>>>(x, Wq, bq, Wk, bk, Wv, bv, Wo, bo, out, nelems);
}